// Round 12
// baseline (148.189 us; speedup 1.0000x reference)
//
#include <hip/hip_runtime.h>

// Algebraic reduction of ECCConv + GlobalSumPool + Dense, fully fused (1 node):
//   out = relu( (sum_e msg[e] + colsum(x)@W_root + N*b_conv) @ W_dense + b_dense )
//   sum_e msg[e,h] = sum_{f,s} T[f,s]*W_kn[s,f*32+h] + sum_f u[f]*b_kn[f*32+h]
//   T[f,s] = sum_e x[src[e],f]*ea[e,s],  u[f] = sum_e x[src[e],f]
//
// R8 lesson: one-thread-per-edge needs acc[80] -> compiler spills (VGPR=68),
// 45 us latency-bound loop. Now each 4-lane group owns one edge: lane j
// reads float4 #j of the x row (coalesced 64B row read) and accumulates a
// 4-feature slice t[4][4]+u[4] (20 floats) -> no spills.
//
// 160->320 blocks; last-arriving block (device-scope counter seeded by the
// deterministic 0xAA ws poison) reduces the 320 slots and finalizes.
// edge_index arrives as int32 (harness integer convention).

#define F_IN 16
#define EDGE_BLOCKS 256
#define X_BLOCKS 64
#define TOTAL_BLOCKS (EDGE_BLOCKS + X_BLOCKS)
#define THREADS 512
#define CNT_OFF 32768u          // float offset; byte 131072 > 320*96*4 = 122880
#define POISON 0xAAAAAAAAu

__global__ __launch_bounds__(THREADS) void fused_kernel(
    const float* __restrict__ x, const int* __restrict__ ei,
    const float* __restrict__ ea, float* __restrict__ ws,
    const float* __restrict__ W_kn, const float* __restrict__ b_kn,
    const float* __restrict__ W_root, const float* __restrict__ b_conv,
    const float* __restrict__ W_dense, const float* __restrict__ b_dense,
    float* __restrict__ out, int N, int E) {
    __shared__ float lred[96];
    __shared__ float red2[96];
    __shared__ float pooled[32];
    __shared__ int   isLast;
    const int bid  = blockIdx.x;
    const int tid  = threadIdx.x;
    const int lane = tid & 63;

    if (tid < 96) { lred[tid] = 0.0f; red2[tid] = 0.0f; }
    __syncthreads();

    if (bid < EDGE_BLOCKS) {
        // ---- 4-lane-per-edge: lane j owns features 4j..4j+3 ----
        const int j = lane & 3;
        float t[4][4], u[4];
        #pragma unroll
        for (int k = 0; k < 4; ++k) {
            u[k] = 0.0f;
            #pragma unroll
            for (int s = 0; s < 4; ++s) t[k][s] = 0.0f;
        }

        const int G = EDGE_BLOCKS * (THREADS / 4);     // total 4-lane groups
        const int g = bid * (THREADS / 4) + (tid >> 2);
        for (int e = g; e < E; e += G) {
            const int srow = ei[(size_t)E + e];        // src row (edge_index[1])
            const float4 a  = *reinterpret_cast<const float4*>(ea + (size_t)e * 4);
            const float4 xv = *reinterpret_cast<const float4*>(x + (size_t)srow * 16 + j * 4);
            const float xk[4] = {xv.x, xv.y, xv.z, xv.w};
            #pragma unroll
            for (int k = 0; k < 4; ++k) {
                u[k] += xk[k];
                t[k][0] = fmaf(xk[k], a.x, t[k][0]);
                t[k][1] = fmaf(xk[k], a.y, t[k][1]);
                t[k][2] = fmaf(xk[k], a.z, t[k][2]);
                t[k][3] = fmaf(xk[k], a.w, t[k][3]);
            }
        }

        // ---- reduce across the 16 groups of the wave (same lane&3 slice) ----
        #pragma unroll
        for (int m = 4; m <= 32; m <<= 1) {
            #pragma unroll
            for (int k = 0; k < 4; ++k) {
                u[k] += __shfl_xor(u[k], m, 64);
                #pragma unroll
                for (int s = 0; s < 4; ++s) t[k][s] += __shfl_xor(t[k][s], m, 64);
            }
        }
        if (lane < 4) {                                // lane j holds slice j
            #pragma unroll
            for (int k = 0; k < 4; ++k) {
                const int f = lane * 4 + k;
                atomicAdd(&lred[64 + f], u[k]);
                #pragma unroll
                for (int s = 0; s < 4; ++s) atomicAdd(&lred[f * 4 + s], t[k][s]);
            }
        }
    } else {
        // ---- column sums of x: cs[16] ----
        const bool b5 = (lane & 32) != 0, b4 = (lane & 16) != 0;
        const bool b3 = (lane & 8)  != 0, b2 = (lane & 4)  != 0;
        float cs[16];
        #pragma unroll
        for (int i = 0; i < 16; ++i) cs[i] = 0.0f;

        const int gtid   = (bid - EDGE_BLOCKS) * THREADS + tid;
        const int stride = X_BLOCKS * THREADS;
        for (int r = gtid; r < N; r += stride) {
            const float4* xr = reinterpret_cast<const float4*>(x + (size_t)r * 16);
            const float4 v0 = xr[0], v1 = xr[1], v2 = xr[2], v3 = xr[3];
            cs[0]+=v0.x; cs[1]+=v0.y; cs[2]+=v0.z;  cs[3]+=v0.w;
            cs[4]+=v1.x; cs[5]+=v1.y; cs[6]+=v1.z;  cs[7]+=v1.w;
            cs[8]+=v2.x; cs[9]+=v2.y; cs[10]+=v2.z; cs[11]+=v2.w;
            cs[12]+=v3.x; cs[13]+=v3.y; cs[14]+=v3.z; cs[15]+=v3.w;
        }
        // fold reduction: value index = (lane>>2) after 4 folds
        #pragma unroll
        for (int i = 0; i < 8; ++i) {
            const float sendv = b5 ? cs[i] : cs[i+8];
            const float keepv = b5 ? cs[i+8] : cs[i];
            cs[i] = keepv + __shfl_xor(sendv, 32, 64);
        }
        #pragma unroll
        for (int i = 0; i < 4; ++i) {
            const float sendv = b4 ? cs[i] : cs[i+4];
            const float keepv = b4 ? cs[i+4] : cs[i];
            cs[i] = keepv + __shfl_xor(sendv, 16, 64);
        }
        #pragma unroll
        for (int i = 0; i < 2; ++i) {
            const float sendv = b3 ? cs[i] : cs[i+2];
            const float keepv = b3 ? cs[i+2] : cs[i];
            cs[i] = keepv + __shfl_xor(sendv, 8, 64);
        }
        {
            const float sendv = b2 ? cs[0] : cs[1];
            const float keepv = b2 ? cs[1] : cs[0];
            cs[0] = keepv + __shfl_xor(sendv, 4, 64);
        }
        cs[0] += __shfl_xor(cs[0], 2, 64);
        cs[0] += __shfl_xor(cs[0], 1, 64);
        if ((lane & 3) == 0) atomicAdd(&lred[80 + (lane >> 2)], cs[0]);
    }
    __syncthreads();

    // ---- publish slot, then release-fence BEFORE the arrival barrier ----
    if (tid < 96) ws[(size_t)bid * 96 + tid] = lred[tid];
    __threadfence();                                   // own writes device-visible
    __syncthreads();                                   // whole block done fencing
    if (tid == 0) {
        unsigned int old = atomicAdd((unsigned int*)(ws + CNT_OFF), 1u);
        isLast = (old == POISON + (unsigned int)(TOTAL_BLOCKS - 1));
    }
    __syncthreads();
    if (!isLast) return;
    __threadfence();                                   // acquire: see all slots

    // ---- last block: reduce 320 slots and finalize ----
    if (tid < 480) {
        const int v = tid / 5, c = tid % 5;            // 5 chunks x 64 blocks
        float s = 0.0f;
        for (int b = c * 64; b < (c + 1) * 64; ++b)
            s += ws[(size_t)b * 96 + v];
        atomicAdd(&red2[v], s);
    }
    __syncthreads();
    if (tid < 32) {
        float p = (float)N * b_conv[tid];
        #pragma unroll
        for (int f = 0; f < 16; ++f) {
            float tsum = 0.0f;
            #pragma unroll
            for (int s = 0; s < 4; ++s)
                tsum = fmaf(red2[f*4+s], W_kn[s*512 + f*32 + tid], tsum);
            p += tsum;
            p = fmaf(red2[64+f], b_kn[f*32+tid], p);
            p = fmaf(red2[80+f], W_root[f*32+tid], p);
        }
        pooled[tid] = p;
    }
    __syncthreads();
    if (tid < 3) {
        float o = b_dense[tid];
        #pragma unroll
        for (int h = 0; h < 32; ++h) o = fmaf(pooled[h], W_dense[h*3+tid], o);
        out[tid] = fmaxf(o, 0.0f);
    }
}

extern "C" void kernel_launch(void* const* d_in, const int* in_sizes, int n_in,
                              void* d_out, int out_size, void* d_ws, size_t ws_size,
                              hipStream_t stream) {
    const float* x       = (const float*)d_in[0];
    const int*   ei      = (const int*)d_in[1];     // int32 (harness convention)
    const float* ea      = (const float*)d_in[2];
    const float* W_kn    = (const float*)d_in[3];
    const float* b_kn    = (const float*)d_in[4];
    const float* W_root  = (const float*)d_in[5];
    const float* b_conv  = (const float*)d_in[6];
    const float* W_dense = (const float*)d_in[7];
    const float* b_dense = (const float*)d_in[8];
    float* ws  = (float*)d_ws;
    float* out = (float*)d_out;

    const int N = in_sizes[0] / F_IN;   // 50000
    const int E = in_sizes[1] / 2;      // 400000

    hipLaunchKernelGGL(fused_kernel, dim3(TOTAL_BLOCKS), dim3(THREADS),
                       0, stream, x, ei, ea, ws,
                       W_kn, b_kn, W_root, b_conv, W_dense, b_dense, out, N, E);
}